// Round 13
// baseline (107.798 us; speedup 1.0000x reference)
//
#include <hip/hip_runtime.h>
#include <hip/hip_bf16.h>
#include <math.h>

typedef __attribute__((ext_vector_type(4)))  float f32x4;
typedef __attribute__((ext_vector_type(16))) float f32x16;
typedef __attribute__((ext_vector_type(8)))  short bf16x8;
typedef __attribute__((ext_vector_type(4)))  int   i32x4;
typedef __attribute__((ext_vector_type(2)))  int   i32x2;

#define NB 2
#define NH 12
#define NS 2048
#define ND 64
#define NKER 9
#define BH (NB*NH)
#define BHS (NB*NH*NS)
#define TK 128            // keys per tile
#define NT (NS/TK)        // 16 tiles

using bf16 = __hip_bfloat16;

__device__ __forceinline__ f32x16 mfma32(bf16x8 a, bf16x8 b, f32x16 c) {
  return __builtin_amdgcn_mfma_f32_32x32x16_bf16(a, b, c, 0, 0, 0);
}

// RNE float->bf16 (finite inputs).
__device__ __forceinline__ unsigned short bf16rne(float f) {
  unsigned u = __builtin_bit_cast(unsigned, f);
  u += 0x7FFFu + ((u >> 16) & 1u);
  return (unsigned short)(u >> 16);
}

// packed RNE: d[15:0]=bf16(lo), d[31:16]=bf16(hi)
__device__ __forceinline__ int cvtpk_bf16(float lo, float hi) {
  int d;
  asm("v_cvt_pk_bf16_f32 %0, %1, %2" : "=v"(d) : "v"(lo), "v"(hi));
  return d;
}

// async global->LDS, 16B per lane; LDS dest wave-uniform base + lane*16.
#define GLDS(gsrc, ldst)                                                     \
  __builtin_amdgcn_global_load_lds(                                          \
      (const __attribute__((address_space(1))) void*)(gsrc),                 \
      (__attribute__((address_space(3))) void*)(ldst), 16, 0, 0)

// ---------------------------------------------------------------------------
// prep: per (bh, 64-seq tile): depthwise conv -> out, masked V^T bf16 -> Vmt,
// and L2-normalized K -> Kn. One pass over K/V.
// ---------------------------------------------------------------------------
__global__ __launch_bounds__(256) void prep(
    const float* __restrict__ K, const float* __restrict__ V,
    const float* __restrict__ mask, const float* __restrict__ cw,
    float* __restrict__ out, bf16* __restrict__ Kn, bf16* __restrict__ Vmt) {
  __shared__ float tile[72][68];
  __shared__ float wsm[NKER];
  int bh = blockIdx.y, b = bh / NH, h = bh % NH;
  int s0 = blockIdx.x * 64;
  int tid = threadIdx.x;
  if (tid < NKER) wsm[tid] = cw[h * NKER + tid];

  int r  = tid >> 2;
  int c0 = (tid & 3) * 16;

  // --- K-normalize rows
  {
    const float* Kr = K + ((size_t)bh * NS + s0 + r) * ND + c0;
    float v[16]; float ss = 0.f;
    #pragma unroll
    for (int j = 0; j < 16; ++j) { v[j] = Kr[j]; ss += v[j] * v[j]; }
    ss += __shfl_xor(ss, 1); ss += __shfl_xor(ss, 2);
    float sc = rsqrtf(fmaxf(ss, 1e-24f));
    bf16x8 o0, o1;
    #pragma unroll
    for (int j = 0; j < 8; ++j) {
      o0[j] = (short)bf16rne(v[j] * sc);
      o1[j] = (short)bf16rne(v[8 + j] * sc);
    }
    bf16* dst = Kn + ((size_t)bh * NS + s0 + r) * ND + c0;
    *(bf16x8*)dst = o0; *(bf16x8*)(dst + 8) = o1;
  }

  // --- masked V halo tile
  #pragma unroll
  for (int pass = 0; pass < 2; ++pass) {
    int rr = r + pass * 64;
    if (pass == 0 || tid < 32) {
      int gs = s0 - NKER / 2 + rr;
      bool ok = (gs >= 0 && gs < NS);
      float m = ok ? mask[b * NS + gs] : 0.f;
      #pragma unroll
      for (int j = 0; j < 16; ++j)
        tile[rr][c0 + j] = ok ? V[((size_t)bh * NS + gs) * ND + c0 + j] * m : 0.f;
    }
  }
  __syncthreads();

  // --- conv
  {
    float acc[16];
    #pragma unroll
    for (int j = 0; j < 16; ++j) acc[j] = 0.f;
    #pragma unroll
    for (int k = 0; k < NKER; ++k) {
      float w = wsm[k];
      #pragma unroll
      for (int j = 0; j < 16; ++j) acc[j] += tile[r + k][c0 + j] * w;
    }
    float* dst = out + ((size_t)bh * NS + s0 + r) * ND + c0;
    #pragma unroll
    for (int j = 0; j < 16; ++j) dst[j] = acc[j];
  }
  // --- V^T (masked, bf16)
  {
    bf16x8 o0, o1;
    #pragma unroll
    for (int j = 0; j < 8; ++j) {
      o0[j] = (short)bf16rne(tile[NKER / 2 + c0 + j][r]);
      o1[j] = (short)bf16rne(tile[NKER / 2 + c0 + 8 + j][r]);
    }
    bf16* dst = Vmt + (size_t)bh * ND * NS + (size_t)r * NS + s0 + c0;
    *(bf16x8*)dst = o0; *(bf16x8*)(dst + 8) = o1;
  }
}

// ---------------------------------------------------------------------------
// Fused YOSO attention. Block = 64 q x 128-key tiles; 8 waves = 2 qsub x 4 kh.
// glds staging, asymmetric buffering in 48 KB (K single 16 KB in-place,
// V double 2x16 KB). Per tile: barA -> K ds_reads + QK^T (setprio) -> barB ->
// glds kt+1 -> transform -> cvt_pk -> permlane32_swap (T12: swaps D.hi<->S.lo;
// swap(pk0,pk2) gives fragment word0 in r[0] and word2 in r[1] -- replaces
// 8 ds_bpermute + 8 cndmask with 4 VALU ops) -> PV (setprio).
// 3 blocks/CU (144 KB, 40 VGPR): whole 768-block grid resident.
// Branch-free transform series; XCD-aware block mapping. Epilogue cmb in LDS.
// ---------------------------------------------------------------------------
__global__ __launch_bounds__(512, 6) void yoso_attn(
    const float* __restrict__ Q, const bf16* __restrict__ Kn,
    const bf16* __restrict__ Vmt, const float* __restrict__ mask,
    float* __restrict__ out) {
  __shared__ __align__(16) char lds[48 * 1024];

  int tid  = threadIdx.x;
  int wave = tid >> 6;
  int lane = tid & 63;
  int ql   = lane & 31;
  int c    = lane >> 5;
  int qsub = wave >> 2;           // 0..1 : 32-q subtile
  int kh   = wave & 3;            // 0..3 : 32-key quarter

  // XCD-aware decode: bx&7 = XCD; each XCD serves bh in {x, x+8, x+16}.
  int bx  = blockIdx.x;
  int idx = bx >> 3;                 // 0..95
  int bh  = (bx & 7) + 8 * (idx >> 5);
  int qg  = idx & 31;
  int b   = bh / NH;
  int q0  = qg * 64;

  const bf16* Kbh = Kn  + (size_t)bh * NS * ND;
  const bf16* Vbh = Vmt + (size_t)bh * ND * NS;

  // ---- Q load + L2-normalize + fragments (B-operand of swapped QK^T)
  bf16x8 aq[4];
  {
    int qrow = q0 + qsub * 32 + ql;
    const float* Qr = Q + ((size_t)bh * NS + qrow) * ND;
    float qv[32]; float ss = 0.f;
    #pragma unroll
    for (int t = 0; t < 4; ++t) {
      f32x4 a0 = *(const f32x4*)(Qr + t * 16 + c * 8);
      f32x4 a1 = *(const f32x4*)(Qr + t * 16 + c * 8 + 4);
      #pragma unroll
      for (int j = 0; j < 4; ++j) {
        qv[t * 8 + j] = a0[j]; qv[t * 8 + 4 + j] = a1[j];
        ss += a0[j] * a0[j] + a1[j] * a1[j];
      }
    }
    ss += __shfl_xor(ss, 32);
    float sc = rsqrtf(fmaxf(ss, 1e-24f));
    #pragma unroll
    for (int t = 0; t < 4; ++t)
      #pragma unroll
      for (int j = 0; j < 8; ++j)
        aq[t][j] = (short)bf16rne(qv[t * 8 + j] * sc);
  }

  f32x16 xa0{}, xa1{};

  // ---- glds staging: per thread 2 K-chunks + 2 V-chunks (16B) per tile.
  // LDS dest linear; XOR swizzle pre-applied to per-lane GLOBAL source.
  int c0i = tid, c1i = tid + 512;
  int k0row = c0i >> 3, k1row = c1i >> 3;
  int v0row = c0i >> 4, v1row = c1i >> 4;
  const char* Ksrc0 = (const char*)Kbh + (size_t)k0row * 128 +
                      (((c0i & 7) * 16) ^ ((k0row & 7) << 4));   // +16384/tile
  const char* Ksrc1 = (const char*)Kbh + (size_t)k1row * 128 +
                      (((c1i & 7) * 16) ^ ((k1row & 7) << 4));
  const char* Vsrc0 = (const char*)Vbh + (size_t)v0row * (NS * 2) +
                      (((c0i & 15) * 16) ^ ((v0row & 7) << 4));  // +256/tile
  const char* Vsrc1 = (const char*)Vbh + (size_t)v1row * (NS * 2) +
                      (((c1i & 15) * 16) ^ ((v1row & 7) << 4));
  char* ldsK = lds + wave * 1024;           // + i*8192 (K buffer at +0)
  char* ldsV = lds + 16384 + wave * 1024;   // + par*16384 + i*8192

  // prologue: stage tile 0 (K -> Kbuf, V -> Vbuf[0])
  GLDS(Ksrc0, ldsK);
  GLDS(Ksrc1, ldsK + 8192);
  GLDS(Vsrc0, ldsV);
  GLDS(Vsrc1, ldsV + 8192);

  // ---- hoisted LDS read offsets
  int krow = kh * 32 + ql;
  int ksw  = (krow & 7) << 4;
  int kboff[4];
  #pragma unroll
  for (int t = 0; t < 4; ++t) kboff[t] = krow * 128 + ((t * 32 + c * 16) ^ ksw);
  int bvoff[2][2];   // relative to V buffer base
  #pragma unroll
  for (int dt = 0; dt < 2; ++dt) {
    int drow = dt * 32 + ql;
    int vsw  = (drow & 7) << 4;
    #pragma unroll
    for (int ks = 0; ks < 2; ++ks)
      bvoff[dt][ks] = drow * 256 + ((kh * 64 + ks * 32 + c * 16) ^ vsw);
  }

  for (int kt = 0; kt < NT; ++kt) {
    __syncthreads();   // barA: glds K(kt), V(kt) landed & visible

    // swapped QK^T: St[key][q] over this wave's 32 keys x 32 q
    bf16x8 ak0 = *(const bf16x8*)(lds + kboff[0]);
    bf16x8 ak1 = *(const bf16x8*)(lds + kboff[1]);
    bf16x8 ak2 = *(const bf16x8*)(lds + kboff[2]);
    bf16x8 ak3 = *(const bf16x8*)(lds + kboff[3]);
    __builtin_amdgcn_s_setprio(1);
    f32x16 s{};
    s = mfma32(ak0, aq[0], s);
    s = mfma32(ak1, aq[1], s);
    s = mfma32(ak2, aq[2], s);
    s = mfma32(ak3, aq[3], s);
    __builtin_amdgcn_s_setprio(0);

    __syncthreads();   // barB: all waves' K reads done; no glds in flight
    if (kt < NT - 1) { // stage kt+1: K in place, V into other buffer.
      GLDS(Ksrc0 + (size_t)(kt + 1) * 16384, ldsK);
      GLDS(Ksrc1 + (size_t)(kt + 1) * 16384, ldsK + 8192);
      char* vdst = ldsV + (((kt + 1) & 1) ? 16384 : 0);
      GLDS(Vsrc0 + (size_t)(kt + 1) * 256, vdst);
      GLDS(Vsrc1 + (size_t)(kt + 1) * 256, vdst + 8192);
    }

    // branch-free transform + pack
    int pk[8];
    #pragma unroll
    for (int g = 0; g < 4; ++g) {
      float wq[4];
      #pragma unroll
      for (int j = 0; j < 4; ++j) {
        float x  = fminf(s[g * 4 + j], 0.999999f);
        float u  = 1.0f - x;
        float sq = __builtin_amdgcn_sqrtf(u);
        float gg = fmaf(fmaf(fmaf(fmaf(8.54787e-4f, u, 2.512043e-3f), u,
                                  8.440465e-3f), u, 3.7513178e-2f), u,
                        0.45015816f);                  // acos(1-u)/(pi*sqrt(u))
        float t1 = fmaf(-sq, gg, 1.0f);                // 1 - acos(x)/pi
        float t2 = t1 * t1, t4 = t2 * t2;
        wq[j] = t4 * t4;
      }
      pk[g * 2]     = cvtpk_bf16(wq[0], wq[1]);
      pk[g * 2 + 1] = cvtpk_bf16(wq[2], wq[3]);
    }
    // T12: permlane32_swap builds A-fragments in 4 VALU ops.
    // swap(D,S): D' = {D.lo, S.lo-values-in-hi-lanes}, S' = {D.hi, S.hi}.
    // pa0 = keys c*8..c*8+7; pa1 = keys 16+c*8..16+c*8+7.
    i32x2 rA = __builtin_amdgcn_permlane32_swap(pk[0], pk[2], false, false);
    i32x2 rB = __builtin_amdgcn_permlane32_swap(pk[1], pk[3], false, false);
    i32x2 rC = __builtin_amdgcn_permlane32_swap(pk[4], pk[6], false, false);
    i32x2 rD = __builtin_amdgcn_permlane32_swap(pk[5], pk[7], false, false);
    i32x4 pa0i = (i32x4){rA[0], rB[0], rA[1], rB[1]};
    i32x4 pa1i = (i32x4){rC[0], rD[0], rC[1], rD[1]};
    bf16x8 pa0 = __builtin_bit_cast(bf16x8, pa0i);
    bf16x8 pa1 = __builtin_bit_cast(bf16x8, pa1i);

    // PV: X[q][d] += P * V^T from Vbuf[kt&1] (disjoint from glds target)
    const char* vbb = lds + 16384 + ((kt & 1) ? 16384 : 0);
    bf16x8 bv00 = *(const bf16x8*)(vbb + bvoff[0][0]);
    bf16x8 bv10 = *(const bf16x8*)(vbb + bvoff[1][0]);
    bf16x8 bv01 = *(const bf16x8*)(vbb + bvoff[0][1]);
    bf16x8 bv11 = *(const bf16x8*)(vbb + bvoff[1][1]);
    __builtin_amdgcn_s_setprio(1);
    xa0 = mfma32(pa0, bv00, xa0);
    xa1 = mfma32(pa0, bv10, xa1);
    xa0 = mfma32(pa1, bv01, xa0);
    xa1 = mfma32(pa1, bv11, xa1);
    __builtin_amdgcn_s_setprio(0);
  }

  // ---- epilogue: combine 4 kh-partials via LDS, mask, L2-norm, += out
  __syncthreads();   // all PV reads done before cmb overlays the buffers
  float (*cmb)[64][64] = (float(*)[64][64])lds;   // [3][64 q][64 d] = 48 KB
  if (kh != 0) {
    #pragma unroll
    for (int r = 0; r < 16; ++r) {
      int qrow = qsub * 32 + (r & 3) + 8 * (r >> 2) + 4 * c;
      cmb[kh - 1][qrow][ql]      = xa0[r];
      cmb[kh - 1][qrow][32 + ql] = xa1[r];
    }
  }
  __syncthreads();
  if (kh == 0) {
    #pragma unroll
    for (int r = 0; r < 16; ++r) {
      int qloc = (r & 3) + 8 * (r >> 2) + 4 * c;
      int qrow = qsub * 32 + qloc;
      int row  = q0 + qrow;
      float m  = mask[b * NS + row];
      float x0 = (xa0[r] + cmb[0][qrow][ql] + cmb[1][qrow][ql] + cmb[2][qrow][ql]) * m;
      float x1 = (xa1[r] + cmb[0][qrow][32 + ql] + cmb[1][qrow][32 + ql] + cmb[2][qrow][32 + ql]) * m;
      float s2 = x0 * x0 + x1 * x1;
      #pragma unroll
      for (int mm = 1; mm < 32; mm <<= 1) s2 += __shfl_xor(s2, mm);
      float sc = rsqrtf(fmaxf(s2, 1e-24f));
      size_t base = ((size_t)bh * NS + row) * ND;
      out[base + ql]      += x0 * sc;
      out[base + 32 + ql] += x1 * sc;
    }
  }
}

// ---------------------------------------------------------------------------
extern "C" void kernel_launch(void* const* d_in, const int* in_sizes, int n_in,
                              void* d_out, int out_size, void* d_ws, size_t ws_size,
                              hipStream_t stream) {
  const float* Q    = (const float*)d_in[0];
  const float* K    = (const float*)d_in[1];
  const float* V    = (const float*)d_in[2];
  const float* mask = (const float*)d_in[3];
  const float* cw   = (const float*)d_in[4];
  float* out = (float*)d_out;

  bf16* Kn  = (bf16*)d_ws;
  bf16* Vmt = Kn + (size_t)BHS * ND;

  prep<<<dim3(NS / 64, BH), 256, 0, stream>>>(K, V, mask, cw, out, Kn, Vmt);
  yoso_attn<<<(NS / 64) * BH, 512, 0, stream>>>(Q, Kn, Vmt, mask, out);
}

// Round 14
// 86.804 us; speedup vs baseline: 1.2419x; 1.2419x over previous
//
#include <hip/hip_runtime.h>
#include <hip/hip_bf16.h>
#include <math.h>

typedef __attribute__((ext_vector_type(4)))  float f32x4;
typedef __attribute__((ext_vector_type(16))) float f32x16;
typedef __attribute__((ext_vector_type(8)))  short bf16x8;
typedef __attribute__((ext_vector_type(4)))  int   i32x4;
typedef __attribute__((ext_vector_type(2)))  int   i32x2;

#define NB 2
#define NH 12
#define NS 2048
#define ND 64
#define NKER 9
#define BH (NB*NH)
#define BHS (NB*NH*NS)
#define TK 128            // keys per tile
#define NT (NS/TK)        // 16 tiles

using bf16 = __hip_bfloat16;

__device__ __forceinline__ f32x16 mfma32(bf16x8 a, bf16x8 b, f32x16 c) {
  return __builtin_amdgcn_mfma_f32_32x32x16_bf16(a, b, c, 0, 0, 0);
}

// RNE float->bf16 (finite inputs).
__device__ __forceinline__ unsigned short bf16rne(float f) {
  unsigned u = __builtin_bit_cast(unsigned, f);
  u += 0x7FFFu + ((u >> 16) & 1u);
  return (unsigned short)(u >> 16);
}

// packed RNE: d[15:0]=bf16(lo), d[31:16]=bf16(hi)
__device__ __forceinline__ int cvtpk_bf16(float lo, float hi) {
  int d;
  asm("v_cvt_pk_bf16_f32 %0, %1, %2" : "=v"(d) : "v"(lo), "v"(hi));
  return d;
}

// async global->LDS, 16B per lane; LDS dest wave-uniform base + lane*16.
#define GLDS(gsrc, ldst)                                                     \
  __builtin_amdgcn_global_load_lds(                                          \
      (const __attribute__((address_space(1))) void*)(gsrc),                 \
      (__attribute__((address_space(3))) void*)(ldst), 16, 0, 0)

// ---------------------------------------------------------------------------
// prep: per (bh, 64-seq tile): depthwise conv -> out, masked V^T bf16 -> Vmt,
// and L2-normalized K -> Kn. One pass over K/V.
// ---------------------------------------------------------------------------
__global__ __launch_bounds__(256) void prep(
    const float* __restrict__ K, const float* __restrict__ V,
    const float* __restrict__ mask, const float* __restrict__ cw,
    float* __restrict__ out, bf16* __restrict__ Kn, bf16* __restrict__ Vmt) {
  __shared__ float tile[72][68];
  __shared__ float wsm[NKER];
  int bh = blockIdx.y, b = bh / NH, h = bh % NH;
  int s0 = blockIdx.x * 64;
  int tid = threadIdx.x;
  if (tid < NKER) wsm[tid] = cw[h * NKER + tid];

  int r  = tid >> 2;
  int c0 = (tid & 3) * 16;

  // --- K-normalize rows
  {
    const float* Kr = K + ((size_t)bh * NS + s0 + r) * ND + c0;
    float v[16]; float ss = 0.f;
    #pragma unroll
    for (int j = 0; j < 16; ++j) { v[j] = Kr[j]; ss += v[j] * v[j]; }
    ss += __shfl_xor(ss, 1); ss += __shfl_xor(ss, 2);
    float sc = rsqrtf(fmaxf(ss, 1e-24f));
    bf16x8 o0, o1;
    #pragma unroll
    for (int j = 0; j < 8; ++j) {
      o0[j] = (short)bf16rne(v[j] * sc);
      o1[j] = (short)bf16rne(v[8 + j] * sc);
    }
    bf16* dst = Kn + ((size_t)bh * NS + s0 + r) * ND + c0;
    *(bf16x8*)dst = o0; *(bf16x8*)(dst + 8) = o1;
  }

  // --- masked V halo tile
  #pragma unroll
  for (int pass = 0; pass < 2; ++pass) {
    int rr = r + pass * 64;
    if (pass == 0 || tid < 32) {
      int gs = s0 - NKER / 2 + rr;
      bool ok = (gs >= 0 && gs < NS);
      float m = ok ? mask[b * NS + gs] : 0.f;
      #pragma unroll
      for (int j = 0; j < 16; ++j)
        tile[rr][c0 + j] = ok ? V[((size_t)bh * NS + gs) * ND + c0 + j] * m : 0.f;
    }
  }
  __syncthreads();

  // --- conv
  {
    float acc[16];
    #pragma unroll
    for (int j = 0; j < 16; ++j) acc[j] = 0.f;
    #pragma unroll
    for (int k = 0; k < NKER; ++k) {
      float w = wsm[k];
      #pragma unroll
      for (int j = 0; j < 16; ++j) acc[j] += tile[r + k][c0 + j] * w;
    }
    float* dst = out + ((size_t)bh * NS + s0 + r) * ND + c0;
    #pragma unroll
    for (int j = 0; j < 16; ++j) dst[j] = acc[j];
  }
  // --- V^T (masked, bf16)
  {
    bf16x8 o0, o1;
    #pragma unroll
    for (int j = 0; j < 8; ++j) {
      o0[j] = (short)bf16rne(tile[NKER / 2 + c0 + j][r]);
      o1[j] = (short)bf16rne(tile[NKER / 2 + c0 + 8 + j][r]);
    }
    bf16* dst = Vmt + (size_t)bh * ND * NS + (size_t)r * NS + s0 + c0;
    *(bf16x8*)dst = o0; *(bf16x8*)(dst + 8) = o1;
  }
}

// ---------------------------------------------------------------------------
// Fused YOSO attention. Block = 64 q x 128-key tiles; 8 waves = 2 qsub x 4 kh.
// glds staging, asymmetric buffering in 48 KB (K single 16 KB in-place,
// V double 2x16 KB). Per tile: barA -> K ds_reads + QK^T -> barB ->
// glds kt+1 -> transform -> cvt_pk -> permlane32_swap (T12: replaces
// 8 ds_bpermute + 8 cndmask with 4 VALU ops) -> PV.
// NO setprio: lockstep blocks (3/CU) are the m190-negative configuration --
// R13 measured it -23 us + FETCH blowup from inter-block issue starvation.
// 3 blocks/CU (144 KB, 40 VGPR): whole 768-block grid resident.
// Branch-free transform series; XCD-aware block mapping. Epilogue cmb in LDS.
// ---------------------------------------------------------------------------
__global__ __launch_bounds__(512, 6) void yoso_attn(
    const float* __restrict__ Q, const bf16* __restrict__ Kn,
    const bf16* __restrict__ Vmt, const float* __restrict__ mask,
    float* __restrict__ out) {
  __shared__ __align__(16) char lds[48 * 1024];

  int tid  = threadIdx.x;
  int wave = tid >> 6;
  int lane = tid & 63;
  int ql   = lane & 31;
  int c    = lane >> 5;
  int qsub = wave >> 2;           // 0..1 : 32-q subtile
  int kh   = wave & 3;            // 0..3 : 32-key quarter

  // XCD-aware decode: bx&7 = XCD; each XCD serves bh in {x, x+8, x+16}.
  int bx  = blockIdx.x;
  int idx = bx >> 3;                 // 0..95
  int bh  = (bx & 7) + 8 * (idx >> 5);
  int qg  = idx & 31;
  int b   = bh / NH;
  int q0  = qg * 64;

  const bf16* Kbh = Kn  + (size_t)bh * NS * ND;
  const bf16* Vbh = Vmt + (size_t)bh * ND * NS;

  // ---- Q load + L2-normalize + fragments (B-operand of swapped QK^T)
  bf16x8 aq[4];
  {
    int qrow = q0 + qsub * 32 + ql;
    const float* Qr = Q + ((size_t)bh * NS + qrow) * ND;
    float qv[32]; float ss = 0.f;
    #pragma unroll
    for (int t = 0; t < 4; ++t) {
      f32x4 a0 = *(const f32x4*)(Qr + t * 16 + c * 8);
      f32x4 a1 = *(const f32x4*)(Qr + t * 16 + c * 8 + 4);
      #pragma unroll
      for (int j = 0; j < 4; ++j) {
        qv[t * 8 + j] = a0[j]; qv[t * 8 + 4 + j] = a1[j];
        ss += a0[j] * a0[j] + a1[j] * a1[j];
      }
    }
    ss += __shfl_xor(ss, 32);
    float sc = rsqrtf(fmaxf(ss, 1e-24f));
    #pragma unroll
    for (int t = 0; t < 4; ++t)
      #pragma unroll
      for (int j = 0; j < 8; ++j)
        aq[t][j] = (short)bf16rne(qv[t * 8 + j] * sc);
  }

  f32x16 xa0{}, xa1{};

  // ---- glds staging: per thread 2 K-chunks + 2 V-chunks (16B) per tile.
  // LDS dest linear; XOR swizzle pre-applied to per-lane GLOBAL source.
  int c0i = tid, c1i = tid + 512;
  int k0row = c0i >> 3, k1row = c1i >> 3;
  int v0row = c0i >> 4, v1row = c1i >> 4;
  const char* Ksrc0 = (const char*)Kbh + (size_t)k0row * 128 +
                      (((c0i & 7) * 16) ^ ((k0row & 7) << 4));   // +16384/tile
  const char* Ksrc1 = (const char*)Kbh + (size_t)k1row * 128 +
                      (((c1i & 7) * 16) ^ ((k1row & 7) << 4));
  const char* Vsrc0 = (const char*)Vbh + (size_t)v0row * (NS * 2) +
                      (((c0i & 15) * 16) ^ ((v0row & 7) << 4));  // +256/tile
  const char* Vsrc1 = (const char*)Vbh + (size_t)v1row * (NS * 2) +
                      (((c1i & 15) * 16) ^ ((v1row & 7) << 4));
  char* ldsK = lds + wave * 1024;           // + i*8192 (K buffer at +0)
  char* ldsV = lds + 16384 + wave * 1024;   // + par*16384 + i*8192

  // prologue: stage tile 0 (K -> Kbuf, V -> Vbuf[0])
  GLDS(Ksrc0, ldsK);
  GLDS(Ksrc1, ldsK + 8192);
  GLDS(Vsrc0, ldsV);
  GLDS(Vsrc1, ldsV + 8192);

  // ---- hoisted LDS read offsets
  int krow = kh * 32 + ql;
  int ksw  = (krow & 7) << 4;
  int kboff[4];
  #pragma unroll
  for (int t = 0; t < 4; ++t) kboff[t] = krow * 128 + ((t * 32 + c * 16) ^ ksw);
  int bvoff[2][2];   // relative to V buffer base
  #pragma unroll
  for (int dt = 0; dt < 2; ++dt) {
    int drow = dt * 32 + ql;
    int vsw  = (drow & 7) << 4;
    #pragma unroll
    for (int ks = 0; ks < 2; ++ks)
      bvoff[dt][ks] = drow * 256 + ((kh * 64 + ks * 32 + c * 16) ^ vsw);
  }

  for (int kt = 0; kt < NT; ++kt) {
    __syncthreads();   // barA: glds K(kt), V(kt) landed & visible

    // swapped QK^T: St[key][q] over this wave's 32 keys x 32 q
    bf16x8 ak0 = *(const bf16x8*)(lds + kboff[0]);
    bf16x8 ak1 = *(const bf16x8*)(lds + kboff[1]);
    bf16x8 ak2 = *(const bf16x8*)(lds + kboff[2]);
    bf16x8 ak3 = *(const bf16x8*)(lds + kboff[3]);
    f32x16 s{};
    s = mfma32(ak0, aq[0], s);
    s = mfma32(ak1, aq[1], s);
    s = mfma32(ak2, aq[2], s);
    s = mfma32(ak3, aq[3], s);

    __syncthreads();   // barB: all waves' K reads done; no glds in flight
    if (kt < NT - 1) { // stage kt+1: K in place, V into other buffer.
      GLDS(Ksrc0 + (size_t)(kt + 1) * 16384, ldsK);
      GLDS(Ksrc1 + (size_t)(kt + 1) * 16384, ldsK + 8192);
      char* vdst = ldsV + (((kt + 1) & 1) ? 16384 : 0);
      GLDS(Vsrc0 + (size_t)(kt + 1) * 256, vdst);
      GLDS(Vsrc1 + (size_t)(kt + 1) * 256, vdst + 8192);
    }

    // branch-free transform + pack
    int pk[8];
    #pragma unroll
    for (int g = 0; g < 4; ++g) {
      float wq[4];
      #pragma unroll
      for (int j = 0; j < 4; ++j) {
        float x  = fminf(s[g * 4 + j], 0.999999f);
        float u  = 1.0f - x;
        float sq = __builtin_amdgcn_sqrtf(u);
        float gg = fmaf(fmaf(fmaf(fmaf(8.54787e-4f, u, 2.512043e-3f), u,
                                  8.440465e-3f), u, 3.7513178e-2f), u,
                        0.45015816f);                  // acos(1-u)/(pi*sqrt(u))
        float t1 = fmaf(-sq, gg, 1.0f);                // 1 - acos(x)/pi
        float t2 = t1 * t1, t4 = t2 * t2;
        wq[j] = t4 * t4;
      }
      pk[g * 2]     = cvtpk_bf16(wq[0], wq[1]);
      pk[g * 2 + 1] = cvtpk_bf16(wq[2], wq[3]);
    }
    // T12: permlane32_swap builds A-fragments in 4 VALU ops.
    i32x2 rA = __builtin_amdgcn_permlane32_swap(pk[0], pk[2], false, false);
    i32x2 rB = __builtin_amdgcn_permlane32_swap(pk[1], pk[3], false, false);
    i32x2 rC = __builtin_amdgcn_permlane32_swap(pk[4], pk[6], false, false);
    i32x2 rD = __builtin_amdgcn_permlane32_swap(pk[5], pk[7], false, false);
    i32x4 pa0i = (i32x4){rA[0], rB[0], rA[1], rB[1]};
    i32x4 pa1i = (i32x4){rC[0], rD[0], rC[1], rD[1]};
    bf16x8 pa0 = __builtin_bit_cast(bf16x8, pa0i);
    bf16x8 pa1 = __builtin_bit_cast(bf16x8, pa1i);

    // PV: X[q][d] += P * V^T from Vbuf[kt&1] (disjoint from glds target)
    const char* vbb = lds + 16384 + ((kt & 1) ? 16384 : 0);
    bf16x8 bv00 = *(const bf16x8*)(vbb + bvoff[0][0]);
    bf16x8 bv10 = *(const bf16x8*)(vbb + bvoff[1][0]);
    bf16x8 bv01 = *(const bf16x8*)(vbb + bvoff[0][1]);
    bf16x8 bv11 = *(const bf16x8*)(vbb + bvoff[1][1]);
    xa0 = mfma32(pa0, bv00, xa0);
    xa1 = mfma32(pa0, bv10, xa1);
    xa0 = mfma32(pa1, bv01, xa0);
    xa1 = mfma32(pa1, bv11, xa1);
  }

  // ---- epilogue: combine 4 kh-partials via LDS, mask, L2-norm, += out
  __syncthreads();   // all PV reads done before cmb overlays the buffers
  float (*cmb)[64][64] = (float(*)[64][64])lds;   // [3][64 q][64 d] = 48 KB
  if (kh != 0) {
    #pragma unroll
    for (int r = 0; r < 16; ++r) {
      int qrow = qsub * 32 + (r & 3) + 8 * (r >> 2) + 4 * c;
      cmb[kh - 1][qrow][ql]      = xa0[r];
      cmb[kh - 1][qrow][32 + ql] = xa1[r];
    }
  }
  __syncthreads();
  if (kh == 0) {
    #pragma unroll
    for (int r = 0; r < 16; ++r) {
      int qloc = (r & 3) + 8 * (r >> 2) + 4 * c;
      int qrow = qsub * 32 + qloc;
      int row  = q0 + qrow;
      float m  = mask[b * NS + row];
      float x0 = (xa0[r] + cmb[0][qrow][ql] + cmb[1][qrow][ql] + cmb[2][qrow][ql]) * m;
      float x1 = (xa1[r] + cmb[0][qrow][32 + ql] + cmb[1][qrow][32 + ql] + cmb[2][qrow][32 + ql]) * m;
      float s2 = x0 * x0 + x1 * x1;
      #pragma unroll
      for (int mm = 1; mm < 32; mm <<= 1) s2 += __shfl_xor(s2, mm);
      float sc = rsqrtf(fmaxf(s2, 1e-24f));
      size_t base = ((size_t)bh * NS + row) * ND;
      out[base + ql]      += x0 * sc;
      out[base + 32 + ql] += x1 * sc;
    }
  }
}

// ---------------------------------------------------------------------------
extern "C" void kernel_launch(void* const* d_in, const int* in_sizes, int n_in,
                              void* d_out, int out_size, void* d_ws, size_t ws_size,
                              hipStream_t stream) {
  const float* Q    = (const float*)d_in[0];
  const float* K    = (const float*)d_in[1];
  const float* V    = (const float*)d_in[2];
  const float* mask = (const float*)d_in[3];
  const float* cw   = (const float*)d_in[4];
  float* out = (float*)d_out;

  bf16* Kn  = (bf16*)d_ws;
  bf16* Vmt = Kn + (size_t)BHS * ND;

  prep<<<dim3(NS / 64, BH), 256, 0, stream>>>(K, V, mask, cw, out, Kn, Vmt);
  yoso_attn<<<(NS / 64) * BH, 512, 0, stream>>>(Q, Kn, Vmt, mask, out);
}